// Round 13
// baseline (2844.396 us; speedup 1.0000x reference)
//
#include <hip/hip_runtime.h>

typedef double d4 __attribute__((ext_vector_type(4)));

static constexpr int BN = 8;
static constexpr int CX = 128;   // x input channels
static constexpr int CO = 128;   // output channels
static constexpr int HH = 64;
static constexpr int WW = 64;
static constexpr int KT = 121;   // 11*11
static constexpr int NPIX = HH * WW;        // 4096
static constexpr int TOTPIX = BN * NPIX;    // 32768

// ---------------------------------------------------------------------------
// K1: transpose W [co][256][11][11] -> WxT/WzT [ci][k][co].
// ---------------------------------------------------------------------------
__global__ __launch_bounds__(128) void k_wt(const float* __restrict__ W,
                                            float* __restrict__ WxT,
                                            float* __restrict__ WzT) {
  int blk  = blockIdx.x;       // part*128 + ci
  int part = blk >> 7;
  int ci   = blk & 127;
  int co   = threadIdx.x;
  const float* src = &W[((co * 256) + part * 128 + ci) * KT];
  float* dst = (part ? WzT : WxT) + ci * KT * 128 + co;
#pragma unroll 11
  for (int k = 0; k < KT; ++k) dst[k * 128] = src[k];
}

// ---------------------------------------------------------------------------
// K2: base = conv(x, W[:, :128]) SAME pad 5, f64 MFMA (v_mfma_f64_16x16x4).
// v4: PER-WAVE private double-buffered x-windows -> ZERO barriers in the
// main loop (LDS ops from one wave execute in order on the DS pipe; buffers
// are wave-private so no cross-wave hazard). Each wave stages its own
// 14x28 window (+4 zero apron rows for pad taps) and free-runs
// load(ci+1) -> MFMA(ci) -> ds_write(ci+1). Weights global->reg per ci
// (coalesced 512B runs, L2-resident). MFMA sequence identical to the
// verified R10-R12 kernels -> bit-identical base.
// Occupancy is register-capped at 4 waves/SIMD (unified VGPR+AGPR ~112);
// grid 1024 = 4 blocks/CU. LDS 32,768 B.
// ---------------------------------------------------------------------------
__global__ __launch_bounds__(256, 4) void k_conv(const float* __restrict__ x,
                                                 const float* __restrict__ WxT,
                                                 double* __restrict__ base) {
  int blk = blockIdx.x;
  int cog = blk & 7;
  int wt  = (blk >> 3) & 3;
  int ht  = (blk >> 5) & 3;
  int b   = blk >> 7;
  int H0 = ht * 16, W0 = wt * 16, CO0 = cog * 16;

  int tid  = threadIdx.x;
  int lane = tid & 63;
  int wv   = tid >> 6;      // wave id -> h sub-tile (4 rows each)
  int lg   = lane >> 4;     // k digit
  int lc   = lane & 15;     // 16-wide digit (co for A, w for B)

  // xs[wave][buf][18*28]: rows 0..13 = x window rows (H0+4*wv-5 .. +8),
  // cols 0..25 valid; rows 14..17 = permanent zero apron for pad taps.
  __shared__ double xs[4][2][504];      // 32,256 B
  __shared__ unsigned offtbl[124];      // element offsets within a buffer

  if (tid < 124) {
    unsigned off;
    if (tid < 121) {
      int ki = tid / 11, kj = tid - ki * 11;
      off = (unsigned)(ki * 28 + kj);
    } else {
      off = (unsigned)(14 * 28);        // zero apron
    }
    offtbl[tid] = off;
  }
  // zero-fill ALL buffers once (apron rows / pad cols stay zero; staging
  // rewrites only what it owns). Cross-wave fill -> one barrier below.
  for (int e = tid; e < 4 * 2 * 504; e += 256) (&xs[0][0][0])[e] = 0.0;

  // --- D-layout probes ---
  d4 zz = {0., 0., 0., 0.};
  double amu  = (double)lc;
  double bsel = (lg == 0) ? 1.0 : 0.0;
  d4 pr = __builtin_amdgcn_mfma_f64_16x16x4f64(amu, bsel, zz, 0, 0, 0);
  d4 pc = __builtin_amdgcn_mfma_f64_16x16x4f64(bsel, amu, zz, 0, 0, 0);

  // --- per-lane staging slots: e = lane + 64*s, s<7 (covers 0..447; data
  // region is e<392 = 14 rows x 28 cols; writes into 392..447 land in the
  // apron and write 0 -> harmless). ---
  unsigned vm = 0;
  int gs[7];
#pragma unroll
  for (int s = 0; s < 7; ++s) {
    int e = lane + 64 * s;
    int r = e / 28, cc = e - r * 28;
    int gh = H0 + wv * 4 - 5 + r;
    int gw = W0 - 5 + cc;
    bool v = (e < 392) && (cc < 26) && ((unsigned)gh < 64u) &&
             ((unsigned)gw < 64u);
    vm |= (v ? 1u : 0u) << s;
    gs[s] = ((b * CX) * HH + gh) * WW + gw;
  }

  __syncthreads();   // offtbl + zero-fill visible to all waves

  double* xA = &xs[wv][0][0];
  double* xB = &xs[wv][1][0];

  // prologue: this wave stages its own ci=0 window into buffer A
  {
#pragma unroll
    for (int s = 0; s < 7; ++s) {
      float xv = 0.f;
      if ((vm >> s) & 1) xv = x[gs[s]];
      xA[lane + 64 * s] = ((vm >> s) & 1) ? (double)xv : 0.0;
    }
  }

  d4 acc0 = {0., 0., 0., 0.};
  d4 acc1 = {0., 0., 0., 0.};
  d4 acc2 = {0., 0., 0., 0.};
  d4 acc3 = {0., 0., 0., 0.};

  // one step: weights(CI) global->reg, prefetch x(CI+1) to regs, MFMA on
  // XRD (wave-local), ds_write x(CI+1) to XWR. NO barriers.
#define CONV_STEP(CI, XRD, XWR, LAST)                                        \
  {                                                                          \
    const float* wci = WxT + (CI) * (KT * 128) + CO0 + lc + lg * 128;        \
    const float* wcl = WxT + (CI) * (KT * 128) + 120 * 128 + CO0 + lc;       \
    float wf[31];                                                            \
    _Pragma("unroll")                                                        \
    for (int c = 0; c < 30; ++c) wf[c] = wci[c * 512];                       \
    {                                                                        \
      float vl = wcl[0];                                                     \
      wf[30] = (lg == 0) ? vl : 0.0f;  /* pad taps 121..123 are zero */      \
    }                                                                        \
    float xv[7];                                                             \
    if (!(LAST)) {                                                           \
      int xo = ((CI) + 1) * (HH * WW);                                       \
      _Pragma("unroll")                                                      \
      for (int s = 0; s < 7; ++s) {                                          \
        xv[s] = 0.f;                                                         \
        if ((vm >> s) & 1) xv[s] = x[gs[s] + xo];                            \
      }                                                                      \
    }                                                                        \
    _Pragma("unroll")                                                        \
    for (int c = 0; c < 31; ++c) {                                           \
      double a = (double)wf[c];                                              \
      unsigned off = offtbl[c * 4 + lg];                                     \
      const double* bp = &(XRD)[lc + off];                                   \
      double b0 = bp[0];                                                     \
      double b1 = bp[28];                                                    \
      double b2 = bp[56];                                                    \
      double b3 = bp[84];                                                    \
      acc0 = __builtin_amdgcn_mfma_f64_16x16x4f64(a, b0, acc0, 0, 0, 0);     \
      acc1 = __builtin_amdgcn_mfma_f64_16x16x4f64(a, b1, acc1, 0, 0, 0);     \
      acc2 = __builtin_amdgcn_mfma_f64_16x16x4f64(a, b2, acc2, 0, 0, 0);     \
      acc3 = __builtin_amdgcn_mfma_f64_16x16x4f64(a, b3, acc3, 0, 0, 0);     \
    }                                                                        \
    if (!(LAST)) {                                                           \
      _Pragma("unroll")                                                      \
      for (int s = 0; s < 7; ++s)                                            \
        (XWR)[lane + 64 * s] = ((vm >> s) & 1) ? (double)xv[s] : 0.0;        \
    }                                                                        \
  }

  for (int ci = 0; ci < 126; ci += 2) {
    CONV_STEP(ci, xA, xB, false)
    CONV_STEP(ci + 1, xB, xA, false)
  }
  CONV_STEP(126, xA, xB, false)
  CONV_STEP(127, xB, xA, true)
#undef CONV_STEP

  // --- epilogue (pixel-major base): slot (lane,i) = (co=CO0+pr[i], w=W0+pc[i])
  int hbase = H0 + wv * 4;
#pragma unroll
  for (int i = 0; i < 4; ++i) {
    int co = CO0 + (int)pr[i];
    int wc = W0 + (int)pc[i];
    double* dst = &base[((size_t)b * NPIX + hbase * 64 + wc) * 128 + co];
    dst[0 * 8192] = acc0[i];
    dst[1 * 8192] = acc1[i];
    dst[2 * 8192] = acc2[i];
    dst[3 * 8192] = acc3[i];
  }
}

// ---------------------------------------------------------------------------
// K3: pixel-PAIR per wave. Half-wave (32 lanes) = one pixel; lane covers a
// co-quad via float4 loads. Unconditional gather via zero-page pointer
// select. Unchanged from the verified R11/R12 kernel.
// ---------------------------------------------------------------------------
__global__ __launch_bounds__(256) void k_step(
    const double* __restrict__ base, const float* __restrict__ WzT,
    const unsigned int* __restrict__ counts,   // [6][128], steps < t valid
    unsigned int* __restrict__ countsT,        // &counts[t*128]
    unsigned int* __restrict__ chgT,           // &chg[t]
    const unsigned char* __restrict__ widxPrev,
    unsigned char* __restrict__ widxCur,
    const float* __restrict__ zf, int t) {
  int wv   = threadIdx.x >> 6;
  int lane = threadIdx.x & 63;
  int hp   = lane >> 5;          // which pixel of the pair
  int l32  = lane & 31;
  int slot = (wv << 1) + hp;
  int pix  = (blockIdx.x << 3) + slot;
  int b  = pix >> 12;
  int hw = pix & 4095;
  int h = hw >> 6, w = hw & 63;
  int co0 = l32 << 2;            // 4 co per lane

  __shared__ int nbrS[8][121];

  // --- bias for the co-quad (sequential, mirrors reference update order) ---
  double bias0 = 0.0, bias1 = 0.0, bias2 = 0.0, bias3 = 0.0;
  for (int s = 0; s < t; ++s) {
    uint4 cv = *reinterpret_cast<const uint4*>(&counts[s * 128 + co0]);
    bias0 += 0.05 * ((double)cv.x * (1.0 / 32768.0) - 1.0 / 128.0);
    bias1 += 0.05 * ((double)cv.y * (1.0 / 32768.0) - 1.0 / 128.0);
    bias2 += 0.05 * ((double)cv.z * (1.0 / 32768.0) - 1.0 / 128.0);
    bias3 += 0.05 * ((double)cv.w * (1.0 / 32768.0) - 1.0 / 128.0);
  }

  // --- stage neighbor winners (each half-wave stages its own pixel) ---
  if (t > 0) {
#pragma unroll
    for (int q = 0; q < 4; ++q) {
      int k = l32 + q * 32;
      if (k < 121) {
        int ki = k / 11, kj = k - ki * 11;
        int nh = h + ki - 5, nw = w + kj - 5;
        int c = 255;
        if ((unsigned)nh < 64u && (unsigned)nw < 64u)
          c = (int)widxPrev[(b << 12) + (nh << 6) + nw];
        nbrS[slot][k] = c;
      }
    }
  }
  __syncthreads();

  double r0, r1, r2, r3;
  {
    const double* bp_ = &base[(size_t)pix * 128 + co0];
    double2 bb0 = *reinterpret_cast<const double2*>(bp_);
    double2 bb1 = *reinterpret_cast<const double2*>(bp_ + 2);
    r0 = bb0.x; r1 = bb0.y; r2 = bb1.x; r3 = bb1.y;
  }

  const float4* zf4 = reinterpret_cast<const float4*>(zf);
  int wpc = 255;
  if (t > 0) {
    const int* nb = nbrS[slot];
    wpc = nb[60];
    double ap[4][4] = {};   // [partial p][co j], fully unrolled -> regs
#pragma unroll 6
    for (int k = 0; k < 120; k += 4) {
      int c0 = nb[k], c1 = nb[k + 1], c2 = nb[k + 2], c3 = nb[k + 3];
      const float4* q0 = (c0 < 128)
          ? reinterpret_cast<const float4*>(&WzT[((c0 * KT + k) << 7) + co0])
          : zf4;
      const float4* q1 = (c1 < 128)
          ? reinterpret_cast<const float4*>(&WzT[((c1 * KT + k + 1) << 7) + co0])
          : zf4;
      const float4* q2 = (c2 < 128)
          ? reinterpret_cast<const float4*>(&WzT[((c2 * KT + k + 2) << 7) + co0])
          : zf4;
      const float4* q3 = (c3 < 128)
          ? reinterpret_cast<const float4*>(&WzT[((c3 * KT + k + 3) << 7) + co0])
          : zf4;
      float4 f0 = *q0, f1 = *q1, f2 = *q2, f3 = *q3;
      ap[0][0] += (double)f0.x; ap[0][1] += (double)f0.y;
      ap[0][2] += (double)f0.z; ap[0][3] += (double)f0.w;
      ap[1][0] += (double)f1.x; ap[1][1] += (double)f1.y;
      ap[1][2] += (double)f1.z; ap[1][3] += (double)f1.w;
      ap[2][0] += (double)f2.x; ap[2][1] += (double)f2.y;
      ap[2][2] += (double)f2.z; ap[2][3] += (double)f2.w;
      ap[3][0] += (double)f3.x; ap[3][1] += (double)f3.y;
      ap[3][2] += (double)f3.z; ap[3][3] += (double)f3.w;
    }
    int cl = nb[120];
    const float4* ql = (cl < 128)
        ? reinterpret_cast<const float4*>(&WzT[((cl * KT + 120) << 7) + co0])
        : zf4;
    float4 fl = *ql;
    ap[0][0] += (double)fl.x; ap[0][1] += (double)fl.y;
    ap[0][2] += (double)fl.z; ap[0][3] += (double)fl.w;
    r0 += (ap[0][0] + ap[1][0]) + (ap[2][0] + ap[3][0]);
    r1 += (ap[0][1] + ap[1][1]) + (ap[2][1] + ap[3][1]);
    r2 += (ap[0][2] + ap[1][2]) + (ap[2][2] + ap[3][2]);
    r3 += (ap[0][3] + ap[1][3]) + (ap[2][3] + ap[3][3]);
  }

  r0 -= bias0; r1 -= bias1; r2 -= bias2; r3 -= bias3;
  if (t > 0) {
    r0 = 0.5 * r0 + ((wpc == co0)     ? 0.5 : 0.0);
    r1 = 0.5 * r1 + ((wpc == co0 + 1) ? 0.5 : 0.0);
    r2 = 0.5 * r2 + ((wpc == co0 + 2) ? 0.5 : 0.0);
    r3 = 0.5 * r3 + ((wpc == co0 + 3) ? 0.5 : 0.0);
  }

  // --- WTA over 128 co within the 32-lane half-wave ---
  double m = fmax(fmax(r0, r1), fmax(r2, r3));
#pragma unroll
  for (int s = 1; s < 32; s <<= 1) m = fmax(m, __shfl_xor(m, s, 32));

  int cand = 255;   // min winning co (descending assignment -> min survives)
  if ((r3 == m) && (r3 > 0.0)) cand = co0 + 3;
  if ((r2 == m) && (r2 > 0.0)) cand = co0 + 2;
  if ((r1 == m) && (r1 > 0.0)) cand = co0 + 1;
  if ((r0 == m) && (r0 > 0.0)) cand = co0;
#pragma unroll
  for (int s = 1; s < 32; s <<= 1) {
    int o = __shfl_xor(cand, s, 32);
    cand = (o < cand) ? o : cand;
  }

  if (l32 == 0) {
    int wi = cand;
    widxCur[pix] = (unsigned char)wi;
    if (wi < 128) atomicAdd(&countsT[wi], 1u);
    if (wpc != wi)
      atomicAdd(chgT, (unsigned)((wpc != 255) + (wi != 255)));
  }
}

// ---------------------------------------------------------------------------
// K4: write changes[0..5] once at the end.
// ---------------------------------------------------------------------------
__global__ __launch_bounds__(64) void k_ch(const unsigned int* __restrict__ chg,
                                           float* __restrict__ outCh) {
  int t = threadIdx.x;
  if (t < 6) outCh[t] = (float)((double)chg[t] * (1.0 / 8388608.0));
}

// ---------------------------------------------------------------------------
// K5: expand winner indices -> features [B][T][CO][H][W], float4 stores.
// ---------------------------------------------------------------------------
__global__ __launch_bounds__(256) void k_feat(const unsigned char* __restrict__ widxA,
                                              float* __restrict__ featBase) {
  int idx = blockIdx.x * 256 + threadIdx.x;     // float4 index
  int hw4 = idx & 1023;
  int co  = (idx >> 10) & 127;
  int bt  = idx >> 17;          // b*6 + t
  int t = bt % 6, b = bt / 6;
  const unsigned char* wp = &widxA[(size_t)(t * BN + b) * 4096 + hw4 * 4];
  float4 o;
  o.x = (wp[0] == co) ? 1.f : 0.f;
  o.y = (wp[1] == co) ? 1.f : 0.f;
  o.z = (wp[2] == co) ? 1.f : 0.f;
  o.w = (wp[3] == co) ? 1.f : 0.f;
  *reinterpret_cast<float4*>(&featBase[(size_t)idx * 4]) = o;
}

// ---------------------------------------------------------------------------
extern "C" void kernel_launch(void* const* d_in, const int* in_sizes, int n_in,
                              void* d_out, int out_size, void* d_ws, size_t ws_size,
                              hipStream_t stream) {
  const float* x = (const float*)d_in[0];
  const float* W = (const float*)d_in[1];
  float* out = (float*)d_out;

  char* ws = (char*)d_ws;
  float* WxT = (float*)ws;                               // 7,929,856 B
  float* WzT = (float*)(ws + 7929856);                   // 7,929,856 B
  double* base = (double*)(ws + 2 * 7929856);            // 33,554,432 B
  char* p = ws + 2 * 7929856 + 33554432;
  unsigned int* counts = (unsigned int*)p; p += 6 * 128 * 4;  // 3072 B
  unsigned int* chg = (unsigned int*)p;    p += 128;     // 32 u32
  float* zf = (float*)p;                   p += 64;      // 16B zero (padded)
  unsigned char* widxA = (unsigned char*)p;              // 6 * 32768 u8

  // zero counts + chg + zf (contiguous 3264 bytes)
  hipMemsetAsync(counts, 0, 3264, stream);

  k_wt<<<256, 128, 0, stream>>>(W, WxT, WzT);
  k_conv<<<1024, 256, 0, stream>>>(x, WxT, base);

  for (int t = 0; t < 6; ++t) {
    unsigned char* wc = widxA + (size_t)t * TOTPIX;
    const unsigned char* wp = (t > 0) ? (widxA + (size_t)(t - 1) * TOTPIX)
                                      : widxA;  // unused at t=0
    k_step<<<4096, 256, 0, stream>>>(base, WzT, counts, counts + t * 128,
                                     chg + t, wp, wc, zf, t);
  }
  k_ch<<<1, 64, 0, stream>>>(chg, out);
  // features: 6*8*128*4096 floats -> 6,291,456 float4 -> 24576 blocks
  k_feat<<<24576, 256, 0, stream>>>(widxA, out + 6);
}

// Round 14
// 2746.607 us; speedup vs baseline: 1.0356x; 1.0356x over previous
//
#include <hip/hip_runtime.h>

typedef double d4 __attribute__((ext_vector_type(4)));

static constexpr int BN = 8;
static constexpr int CX = 128;   // x input channels
static constexpr int CO = 128;   // output channels
static constexpr int HH = 64;
static constexpr int WW = 64;
static constexpr int KT = 121;   // 11*11
static constexpr int NPIX = HH * WW;        // 4096
static constexpr int TOTPIX = BN * NPIX;    // 32768

// ---------------------------------------------------------------------------
// K1: transpose W [co][256][11][11] -> WxT/WzT [ci][k][co].
// ---------------------------------------------------------------------------
__global__ __launch_bounds__(128) void k_wt(const float* __restrict__ W,
                                            float* __restrict__ WxT,
                                            float* __restrict__ WzT) {
  int blk  = blockIdx.x;       // part*128 + ci
  int part = blk >> 7;
  int ci   = blk & 127;
  int co   = threadIdx.x;
  const float* src = &W[((co * 256) + part * 128 + ci) * KT];
  float* dst = (part ? WzT : WxT) + ci * KT * 128 + co;
#pragma unroll 11
  for (int k = 0; k < KT; ++k) dst[k * 128] = src[k];
}

// ---------------------------------------------------------------------------
// K2: base = conv(x, W[:, :128]) SAME pad 5, f64 MFMA (v_mfma_f64_16x16x4).
// v1 structure (verified best of 5 variants, R10: 2165 us, MfmaUtil 87%):
// LDS-staged f64 weights + x window, register prefetch of ci+1 issued
// before ci's MFMA phase, 2 barriers per ci. Pixel-major base[b][hw][co];
// D-layout probe calibration. Grid 1024 = 4/CU (reg-capped). LDS 25,776 B.
// ---------------------------------------------------------------------------
__global__ __launch_bounds__(256, 4) void k_conv(const float* __restrict__ x,
                                                 const float* __restrict__ WxT,
                                                 double* __restrict__ base) {
  int blk = blockIdx.x;
  int cog = blk & 7;
  int wt  = (blk >> 3) & 3;
  int ht  = (blk >> 5) & 3;
  int b   = blk >> 7;
  int H0 = ht * 16, W0 = wt * 16, CO0 = cog * 16;

  int tid  = threadIdx.x;
  int lane = tid & 63;
  int wv   = tid >> 6;      // wave id -> h sub-tile (4 rows each)
  int lg   = lane >> 4;     // k digit
  int lc   = lane & 15;     // 16-wide digit (co for A, w for B)

  __shared__ double xs[42 * 28];        // 9408 B (rows 26..41 = zero apron)
  __shared__ double wsl[124 * 16];      // 15872 B, k>=121 zeroed once
  __shared__ unsigned offtbl[124];      // element offsets into xs

  if (tid < 124) {
    unsigned off;
    if (tid < 121) {
      int ki = tid / 11, kj = tid - ki * 11;
      off = (unsigned)(ki * 28 + kj);
    } else {
      off = (unsigned)(26 * 28);        // zero apron
    }
    offtbl[tid] = off;
  }
  for (int e = tid; e < 42 * 28; e += 256) xs[e] = 0.0;
  if (tid < 48) wsl[121 * 16 + tid] = 0.0;   // pad rows zeroed once

  // --- D-layout probes ---
  d4 zz = {0., 0., 0., 0.};
  double amu  = (double)lc;
  double bsel = (lg == 0) ? 1.0 : 0.0;
  d4 pr = __builtin_amdgcn_mfma_f64_16x16x4f64(amu, bsel, zz, 0, 0, 0);
  d4 pc = __builtin_amdgcn_mfma_f64_16x16x4f64(bsel, amu, zz, 0, 0, 0);

  // --- per-thread staging slots (ci-invariant) ---
  int e0 = tid, e1 = tid + 256, e2 = tid + 512;   // x slots, e<728 valid
  bool v0 = false, v1 = false, v2 = false;
  int g0 = 0, g1 = 0, g2 = 0;
  {
    int e = e0; int r = e / 28, cc = e - r * 28;
    int gh = H0 - 5 + r, gw = W0 - 5 + cc;
    v0 = (cc < 26) && ((unsigned)gh < 64u) && ((unsigned)gw < 64u);
    g0 = ((b * CX) * HH + gh) * WW + gw;
  }
  {
    int e = e1; int r = e / 28, cc = e - r * 28;
    int gh = H0 - 5 + r, gw = W0 - 5 + cc;
    v1 = (cc < 26) && ((unsigned)gh < 64u) && ((unsigned)gw < 64u);
    g1 = ((b * CX) * HH + gh) * WW + gw;
  }
  if (e2 < 728) {
    int e = e2; int r = e / 28, cc = e - r * 28;
    int gh = H0 - 5 + r, gw = W0 - 5 + cc;
    v2 = (cc < 26) && ((unsigned)gh < 64u) && ((unsigned)gw < 64u);
    g2 = ((b * CX) * HH + gh) * WW + gw;
  }
  bool wact = (tid < 242);            // k = tid>>1 <= 120
  int wk = tid >> 1;
  int wgoff = wk * 128 + CO0 + (tid & 1) * 8;

  float xv0 = 0.f, xv1 = 0.f, xv2 = 0.f;
  float4 wva = {0, 0, 0, 0}, wvb = {0, 0, 0, 0};

  // prologue: load + stage ci=0
  {
    if (v0) xv0 = x[g0];
    if (v1) xv1 = x[g1];
    if (v2) xv2 = x[g2];
    if (wact) {
      wva = *reinterpret_cast<const float4*>(&WxT[wgoff]);
      wvb = *reinterpret_cast<const float4*>(&WxT[wgoff + 4]);
    }
    if (e0 < 728) xs[e0] = v0 ? (double)xv0 : 0.0;
    if (e1 < 728) xs[e1] = v1 ? (double)xv1 : 0.0;
    if (e2 < 728) xs[e2] = v2 ? (double)xv2 : 0.0;
    if (wact) {
      double* dst = &wsl[wk * 16 + (tid & 1) * 8];
      dst[0] = (double)wva.x; dst[1] = (double)wva.y;
      dst[2] = (double)wva.z; dst[3] = (double)wva.w;
      dst[4] = (double)wvb.x; dst[5] = (double)wvb.y;
      dst[6] = (double)wvb.z; dst[7] = (double)wvb.w;
    }
  }
  __syncthreads();

  d4 acc0 = {0., 0., 0., 0.};
  d4 acc1 = {0., 0., 0., 0.};
  d4 acc2 = {0., 0., 0., 0.};
  d4 acc3 = {0., 0., 0., 0.};

  unsigned xbase = (unsigned)(wv * 112 + lc);

  for (int ci = 0; ci < CX; ++ci) {
    // issue next-ci global loads (consumed only after the barrier below)
    if (ci < CX - 1) {
      int xo = (ci + 1) * (HH * WW);
      int wo = (ci + 1) * (KT * 128);
      if (v0) xv0 = x[g0 + xo];
      if (v1) xv1 = x[g1 + xo];
      if (v2) xv2 = x[g2 + xo];
      if (wact) {
        wva = *reinterpret_cast<const float4*>(&WxT[wo + wgoff]);
        wvb = *reinterpret_cast<const float4*>(&WxT[wo + wgoff + 4]);
      }
    }

    // --- 31 K-chunks of 4 taps (MFMA on LDS(ci)) ---
#pragma unroll 31
    for (int c = 0; c < 31; ++c) {
      double a = wsl[(unsigned)(c * 64 + lg * 16 + lc)];
      unsigned off = offtbl[(unsigned)(c * 4 + lg)];
      const double* bp = &xs[xbase + off];
      double b0 = bp[0];
      double b1 = bp[28];
      double b2 = bp[56];
      double b3 = bp[84];
      acc0 = __builtin_amdgcn_mfma_f64_16x16x4f64(a, b0, acc0, 0, 0, 0);
      acc1 = __builtin_amdgcn_mfma_f64_16x16x4f64(a, b1, acc1, 0, 0, 0);
      acc2 = __builtin_amdgcn_mfma_f64_16x16x4f64(a, b2, acc2, 0, 0, 0);
      acc3 = __builtin_amdgcn_mfma_f64_16x16x4f64(a, b3, acc3, 0, 0, 0);
    }
    __syncthreads();

    if (ci < CX - 1) {
      if (e0 < 728) xs[e0] = v0 ? (double)xv0 : 0.0;
      if (e1 < 728) xs[e1] = v1 ? (double)xv1 : 0.0;
      if (e2 < 728) xs[e2] = v2 ? (double)xv2 : 0.0;
      if (wact) {
        double* dst = &wsl[wk * 16 + (tid & 1) * 8];
        dst[0] = (double)wva.x; dst[1] = (double)wva.y;
        dst[2] = (double)wva.z; dst[3] = (double)wva.w;
        dst[4] = (double)wvb.x; dst[5] = (double)wvb.y;
        dst[6] = (double)wvb.z; dst[7] = (double)wvb.w;
      }
      __syncthreads();
    }
  }

  // --- epilogue (pixel-major base): slot (lane,i) = (co=CO0+pr[i], w=W0+pc[i])
  int hbase = H0 + wv * 4;
#pragma unroll
  for (int i = 0; i < 4; ++i) {
    int co = CO0 + (int)pr[i];
    int wc = W0 + (int)pc[i];
    double* dst = &base[((size_t)b * NPIX + hbase * 64 + wc) * 128 + co];
    dst[0 * 8192] = acc0[i];
    dst[1 * 8192] = acc1[i];
    dst[2 * 8192] = acc2[i];
    dst[3 * 8192] = acc3[i];
  }
}

// ---------------------------------------------------------------------------
// K3: pixel-PAIR per wave. Half-wave (32 lanes) = one pixel; lane covers a
// co-quad via float4 loads. Unconditional gather via zero-page pointer
// select. Unchanged from the verified R11/R12 kernel.
// ---------------------------------------------------------------------------
__global__ __launch_bounds__(256) void k_step(
    const double* __restrict__ base, const float* __restrict__ WzT,
    const unsigned int* __restrict__ counts,   // [6][128], steps < t valid
    unsigned int* __restrict__ countsT,        // &counts[t*128]
    unsigned int* __restrict__ chgT,           // &chg[t]
    const unsigned char* __restrict__ widxPrev,
    unsigned char* __restrict__ widxCur,
    const float* __restrict__ zf, int t) {
  int wv   = threadIdx.x >> 6;
  int lane = threadIdx.x & 63;
  int hp   = lane >> 5;          // which pixel of the pair
  int l32  = lane & 31;
  int slot = (wv << 1) + hp;
  int pix  = (blockIdx.x << 3) + slot;
  int b  = pix >> 12;
  int hw = pix & 4095;
  int h = hw >> 6, w = hw & 63;
  int co0 = l32 << 2;            // 4 co per lane

  __shared__ int nbrS[8][121];

  // --- bias for the co-quad (sequential, mirrors reference update order) ---
  double bias0 = 0.0, bias1 = 0.0, bias2 = 0.0, bias3 = 0.0;
  for (int s = 0; s < t; ++s) {
    uint4 cv = *reinterpret_cast<const uint4*>(&counts[s * 128 + co0]);
    bias0 += 0.05 * ((double)cv.x * (1.0 / 32768.0) - 1.0 / 128.0);
    bias1 += 0.05 * ((double)cv.y * (1.0 / 32768.0) - 1.0 / 128.0);
    bias2 += 0.05 * ((double)cv.z * (1.0 / 32768.0) - 1.0 / 128.0);
    bias3 += 0.05 * ((double)cv.w * (1.0 / 32768.0) - 1.0 / 128.0);
  }

  // --- stage neighbor winners (each half-wave stages its own pixel) ---
  if (t > 0) {
#pragma unroll
    for (int q = 0; q < 4; ++q) {
      int k = l32 + q * 32;
      if (k < 121) {
        int ki = k / 11, kj = k - ki * 11;
        int nh = h + ki - 5, nw = w + kj - 5;
        int c = 255;
        if ((unsigned)nh < 64u && (unsigned)nw < 64u)
          c = (int)widxPrev[(b << 12) + (nh << 6) + nw];
        nbrS[slot][k] = c;
      }
    }
  }
  __syncthreads();

  double r0, r1, r2, r3;
  {
    const double* bp_ = &base[(size_t)pix * 128 + co0];
    double2 bb0 = *reinterpret_cast<const double2*>(bp_);
    double2 bb1 = *reinterpret_cast<const double2*>(bp_ + 2);
    r0 = bb0.x; r1 = bb0.y; r2 = bb1.x; r3 = bb1.y;
  }

  const float4* zf4 = reinterpret_cast<const float4*>(zf);
  int wpc = 255;
  if (t > 0) {
    const int* nb = nbrS[slot];
    wpc = nb[60];
    double ap[4][4] = {};   // [partial p][co j], fully unrolled -> regs
#pragma unroll 6
    for (int k = 0; k < 120; k += 4) {
      int c0 = nb[k], c1 = nb[k + 1], c2 = nb[k + 2], c3 = nb[k + 3];
      const float4* q0 = (c0 < 128)
          ? reinterpret_cast<const float4*>(&WzT[((c0 * KT + k) << 7) + co0])
          : zf4;
      const float4* q1 = (c1 < 128)
          ? reinterpret_cast<const float4*>(&WzT[((c1 * KT + k + 1) << 7) + co0])
          : zf4;
      const float4* q2 = (c2 < 128)
          ? reinterpret_cast<const float4*>(&WzT[((c2 * KT + k + 2) << 7) + co0])
          : zf4;
      const float4* q3 = (c3 < 128)
          ? reinterpret_cast<const float4*>(&WzT[((c3 * KT + k + 3) << 7) + co0])
          : zf4;
      float4 f0 = *q0, f1 = *q1, f2 = *q2, f3 = *q3;
      ap[0][0] += (double)f0.x; ap[0][1] += (double)f0.y;
      ap[0][2] += (double)f0.z; ap[0][3] += (double)f0.w;
      ap[1][0] += (double)f1.x; ap[1][1] += (double)f1.y;
      ap[1][2] += (double)f1.z; ap[1][3] += (double)f1.w;
      ap[2][0] += (double)f2.x; ap[2][1] += (double)f2.y;
      ap[2][2] += (double)f2.z; ap[2][3] += (double)f2.w;
      ap[3][0] += (double)f3.x; ap[3][1] += (double)f3.y;
      ap[3][2] += (double)f3.z; ap[3][3] += (double)f3.w;
    }
    int cl = nb[120];
    const float4* ql = (cl < 128)
        ? reinterpret_cast<const float4*>(&WzT[((cl * KT + 120) << 7) + co0])
        : zf4;
    float4 fl = *ql;
    ap[0][0] += (double)fl.x; ap[0][1] += (double)fl.y;
    ap[0][2] += (double)fl.z; ap[0][3] += (double)fl.w;
    r0 += (ap[0][0] + ap[1][0]) + (ap[2][0] + ap[3][0]);
    r1 += (ap[0][1] + ap[1][1]) + (ap[2][1] + ap[3][1]);
    r2 += (ap[0][2] + ap[1][2]) + (ap[2][2] + ap[3][2]);
    r3 += (ap[0][3] + ap[1][3]) + (ap[2][3] + ap[3][3]);
  }

  r0 -= bias0; r1 -= bias1; r2 -= bias2; r3 -= bias3;
  if (t > 0) {
    r0 = 0.5 * r0 + ((wpc == co0)     ? 0.5 : 0.0);
    r1 = 0.5 * r1 + ((wpc == co0 + 1) ? 0.5 : 0.0);
    r2 = 0.5 * r2 + ((wpc == co0 + 2) ? 0.5 : 0.0);
    r3 = 0.5 * r3 + ((wpc == co0 + 3) ? 0.5 : 0.0);
  }

  // --- WTA over 128 co within the 32-lane half-wave ---
  double m = fmax(fmax(r0, r1), fmax(r2, r3));
#pragma unroll
  for (int s = 1; s < 32; s <<= 1) m = fmax(m, __shfl_xor(m, s, 32));

  int cand = 255;   // min winning co (descending assignment -> min survives)
  if ((r3 == m) && (r3 > 0.0)) cand = co0 + 3;
  if ((r2 == m) && (r2 > 0.0)) cand = co0 + 2;
  if ((r1 == m) && (r1 > 0.0)) cand = co0 + 1;
  if ((r0 == m) && (r0 > 0.0)) cand = co0;
#pragma unroll
  for (int s = 1; s < 32; s <<= 1) {
    int o = __shfl_xor(cand, s, 32);
    cand = (o < cand) ? o : cand;
  }

  if (l32 == 0) {
    int wi = cand;
    widxCur[pix] = (unsigned char)wi;
    if (wi < 128) atomicAdd(&countsT[wi], 1u);
    if (wpc != wi)
      atomicAdd(chgT, (unsigned)((wpc != 255) + (wi != 255)));
  }
}

// ---------------------------------------------------------------------------
// K4: write changes[0..5] once at the end.
// ---------------------------------------------------------------------------
__global__ __launch_bounds__(64) void k_ch(const unsigned int* __restrict__ chg,
                                           float* __restrict__ outCh) {
  int t = threadIdx.x;
  if (t < 6) outCh[t] = (float)((double)chg[t] * (1.0 / 8388608.0));
}

// ---------------------------------------------------------------------------
// K5: expand winner indices -> features [B][T][CO][H][W], float4 stores.
// ---------------------------------------------------------------------------
__global__ __launch_bounds__(256) void k_feat(const unsigned char* __restrict__ widxA,
                                              float* __restrict__ featBase) {
  int idx = blockIdx.x * 256 + threadIdx.x;     // float4 index
  int hw4 = idx & 1023;
  int co  = (idx >> 10) & 127;
  int bt  = idx >> 17;          // b*6 + t
  int t = bt % 6, b = bt / 6;
  const unsigned char* wp = &widxA[(size_t)(t * BN + b) * 4096 + hw4 * 4];
  float4 o;
  o.x = (wp[0] == co) ? 1.f : 0.f;
  o.y = (wp[1] == co) ? 1.f : 0.f;
  o.z = (wp[2] == co) ? 1.f : 0.f;
  o.w = (wp[3] == co) ? 1.f : 0.f;
  *reinterpret_cast<float4*>(&featBase[(size_t)idx * 4]) = o;
}

// ---------------------------------------------------------------------------
extern "C" void kernel_launch(void* const* d_in, const int* in_sizes, int n_in,
                              void* d_out, int out_size, void* d_ws, size_t ws_size,
                              hipStream_t stream) {
  const float* x = (const float*)d_in[0];
  const float* W = (const float*)d_in[1];
  float* out = (float*)d_out;

  char* ws = (char*)d_ws;
  float* WxT = (float*)ws;                               // 7,929,856 B
  float* WzT = (float*)(ws + 7929856);                   // 7,929,856 B
  double* base = (double*)(ws + 2 * 7929856);            // 33,554,432 B
  char* p = ws + 2 * 7929856 + 33554432;
  unsigned int* counts = (unsigned int*)p; p += 6 * 128 * 4;  // 3072 B
  unsigned int* chg = (unsigned int*)p;    p += 128;     // 32 u32
  float* zf = (float*)p;                   p += 64;      // 16B zero (padded)
  unsigned char* widxA = (unsigned char*)p;              // 6 * 32768 u8

  // zero counts + chg + zf (contiguous 3264 bytes)
  hipMemsetAsync(counts, 0, 3264, stream);

  k_wt<<<256, 128, 0, stream>>>(W, WxT, WzT);
  k_conv<<<1024, 256, 0, stream>>>(x, WxT, base);

  for (int t = 0; t < 6; ++t) {
    unsigned char* wc = widxA + (size_t)t * TOTPIX;
    const unsigned char* wp = (t > 0) ? (widxA + (size_t)(t - 1) * TOTPIX)
                                      : widxA;  // unused at t=0
    k_step<<<4096, 256, 0, stream>>>(base, WzT, counts, counts + t * 128,
                                     chg + t, wp, wc, zf, t);
  }
  k_ch<<<1, 64, 0, stream>>>(chg, out);
  // features: 6*8*128*4096 floats -> 6,291,456 float4 -> 24576 blocks
  k_feat<<<24576, 256, 0, stream>>>(widxA, out + 6);
}